// Round 8
// baseline (230.773 us; speedup 1.0000x reference)
//
#include <hip/hip_runtime.h>

namespace {
constexpr int T_STEPS = 50;
constexpr int BATCH_N = 131072;
constexpr int HIDDEN  = 100;
}

// Pre-kernel: interleave weights into d_ws as [h][4] = {w1a, w1b, w20, w21}
// so the main kernel does uniform 16B-aligned reads (-> scalar loads).
__global__ void interleave_weights(const float* __restrict__ W1,
                                   const float* __restrict__ W2,
                                   float* __restrict__ wi) {
    int h = blockIdx.x * 64 + threadIdx.x;
    if (h < HIDDEN) {
        wi[4 * h + 0] = W1[2 * h];          // W1[h][0]
        wi[4 * h + 1] = W1[2 * h + 1];      // W1[h][1]
        wi[4 * h + 2] = W2[h];              // W2[0][h]
        wi[4 * h + 3] = W2[HIDDEN + h];     // W2[1][h]
    }
}

// t-outer / h-inner (h fully unrolled). State = m1[100] in registers only;
// x streams per t; acc0/acc1 scalar; outputs stored per t.
// Arithmetic is bitwise-identical to the R7 PASS:
//   cur  = fmaf(x1, w1b, x0*w1a)
//   mem  = fmaf(spk_prev, -0.5f, fmaf(0.9f, mem, cur))
//   spk  = (mem > 0.5f) ? 1.0f : 0.0f      (spk_prev recomputed from m[h])
//   acc  = ascending-h serial fmaf chain
__global__ __launch_bounds__(256)
void snn_touter(const unsigned int* __restrict__ x_u,
                const float* __restrict__ wi,
                unsigned int* __restrict__ out_u)
{
#pragma clang fp contract(off)
    const int b = blockIdx.x * 256 + threadIdx.x;

    float m[HIDDEN];
#pragma unroll
    for (int h = 0; h < HIDDEN; ++h) m[h] = 0.0f;

    float m20 = 0.0f, m21 = 0.0f, s20 = 0.0f, s21 = 0.0f;  // layer-2 state
    const size_t mem_off = (size_t)T_STEPS * BATCH_N * 2;

    for (int t = 0; t < T_STEPS; ++t) {
        const size_t cell = ((size_t)t * BATCH_N + b) * 2;
        const float x0 = __uint_as_float(x_u[cell]);
        const float x1 = __uint_as_float(x_u[cell + 1]);

        float acc0 = 0.0f, acc1 = 0.0f;
#pragma unroll
        for (int h = 0; h < HIDDEN; ++h) {
            const float w1a = wi[4 * h + 0];   // uniform -> s_load
            const float w1b = wi[4 * h + 1];
            const float w20 = wi[4 * h + 2];
            const float w21 = wi[4 * h + 3];
            const float cur = fmaf(x1, w1b, x0 * w1a);
            const float sp  = (m[h] > 0.5f) ? 1.0f : 0.0f;   // spk from t-1
            const float mn  = fmaf(sp, -0.5f, fmaf(0.9f, m[h], cur));
            m[h] = mn;
            const float sc  = (mn > 0.5f) ? 1.0f : 0.0f;     // spk at t
            acc0 = fmaf(sc, w20, acc0);
            acc1 = fmaf(sc, w21, acc1);
        }

        // Layer-2 recurrence (s20/s21 carried across t in registers).
        m20 = fmaf(s20, -0.5f, fmaf(0.9f, m20, acc0));
        m21 = fmaf(s21, -0.5f, fmaf(0.9f, m21, acc1));
        s20 = (m20 > 0.5f) ? 1.0f : 0.0f;
        s21 = (m21 > 0.5f) ? 1.0f : 0.0f;

        out_u[cell]               = __float_as_uint(s20);
        out_u[cell + 1]           = __float_as_uint(s21);
        out_u[mem_off + cell]     = __float_as_uint(m20);
        out_u[mem_off + cell + 1] = __float_as_uint(m21);
    }
}

extern "C" void kernel_launch(void* const* d_in, const int* in_sizes, int n_in,
                              void* d_out, int out_size, void* d_ws, size_t ws_size,
                              hipStream_t stream) {
    // Robust input mapping: x = the unique large buffer; W1 precedes W2 among
    // the rest (holds under both dict order [x,W1,W2] and sorted [W1,W2,x]).
    int big = 0;
    for (int i = 1; i < n_in; ++i) if (in_sizes[i] > in_sizes[big]) big = i;
    const void* ptrs[3] = {nullptr, nullptr, nullptr};  // x, W1, W2
    int k = 1;
    ptrs[0] = d_in[big];
    for (int i = 0; i < n_in; ++i) {
        if (i == big) continue;
        ptrs[k++] = d_in[i];
    }
    const unsigned int* x_u = (const unsigned int*)ptrs[0];
    const float* W1 = (const float*)ptrs[1];
    const float* W2 = (const float*)ptrs[2];
    float* wi = (float*)d_ws;                 // 400 floats = 1600 B scratch
    unsigned int* out_u = (unsigned int*)d_out;

    hipLaunchKernelGGL(interleave_weights, dim3(2), dim3(64), 0, stream,
                       W1, W2, wi);
    hipLaunchKernelGGL(snn_touter, dim3(BATCH_N / 256), dim3(256), 0, stream,
                       x_u, wi, out_u);
}